// Round 1
// 73.720 us; speedup vs baseline: 1.0088x; 1.0088x over previous
//
#include <hip/hip_runtime.h>

#define HH 320
#define WW 320
#define BIGF 1.0e5f

// ---- Kernel 1: vertical 1D distance, chunked parallel scan ----
// One (image, channel) per block now: grid 160 blocks (was 80) for 2x CU
// coverage. Channel pairs read the same float2 cache lines -> no extra HBM.
#define TW  16
#define NCH 32
#define CH  10

__global__ __launch_bounds__(512) void edt_vert(const float* __restrict__ in,
                                                float* __restrict__ g2) {
    int wl = threadIdx.x;            // 0..15 column within tile
    int ch = threadIdx.y;            // 0..31 h-chunk
    int bc = blockIdx.x / 20;        // 0..7 = b*2 + c (matches g2 layout)
    int wt = blockIdx.x % 20;
    int b  = bc >> 1;
    int c  = bc & 1;
    int w  = wt * TW + wl;
    int h0 = ch * CH;

    const float2* ip = (const float2*)in + (size_t)(b * HH + h0) * WW + w;
    float vv[CH];
    #pragma unroll
    for (int k = 0; k < CH; ++k) {
        float2 t = ip[(size_t)k * WW];
        vv[k] = c ? t.y : t.x;       // c is block-uniform
    }

    unsigned m0 = 0;
    #pragma unroll
    for (int k = 0; k < CH; ++k)
        if ((1.0f - vv[k]) * 127.5f < 1.0f) m0 |= 1u << k;   // uint8 restore == 0

    __shared__ float sL[NCH][TW], sN[NCH][TW];
    sL[ch][wl] = m0 ? (float)(h0 + 31 - __clz((int)m0)) : -1.0e9f;
    sN[ch][wl] = m0 ? (float)(h0 + __ffs((int)m0) - 1)  :  1.0e9f;
    __syncthreads();

    float L0 = -1.0e9f, N0 = 1.0e9f;
    for (int cc = 0; cc < NCH; ++cc) {
        float a0 = sL[cc][wl];
        float b0 = sN[cc][wl];
        if (cc < ch) L0 = fmaxf(L0, a0);
        if (cc > ch) N0 = fminf(N0, b0);
    }

    float gd0[CH];
    float r0 = L0;
    #pragma unroll
    for (int k = 0; k < CH; ++k) {
        float fh = (float)(h0 + k);
        if (m0 & (1u << k)) r0 = fh;
        gd0[k] = fh - r0;
    }
    float* gp0 = g2 + ((size_t)bc * HH + h0) * WW + w;
    r0 = N0;
    #pragma unroll
    for (int k = CH - 1; k >= 0; --k) {
        float fh = (float)(h0 + k);
        if (m0 & (1u << k)) r0 = fh;
        float g0 = fminf(fminf(gd0[k], r0 - fh), BIGF);
        gp0[(size_t)k * WW] = g0 * g0;
    }
}

// ---- Kernel 2: blind exact lower envelope, load-balanced ----
// Grid = 4 imgs x 320 rows = 1280 blocks x 256 thr -> exactly 5 blocks/CU,
// 5 waves/SIMD (was 640 blocks @ 2.5/CU -> 2-vs-3 block imbalance, ~30% tax).
// Block handles one row, both channels; each (row,channel) is split across
// TWO waves by x-half (wave wv: c = wv>>1, half = wv&1). Each wave evaluates
// all 320 j's against its 160 x's; halves are min-combined through LDS.
// Candidate values are bit-identical to the previous verified kernel
// (same fmaf args, fminf is order-invariant, all ints exact in f32).
__global__ __launch_bounds__(256, 5) void edt_horiz(const float* __restrict__ g2,
                                                    float* __restrict__ out) {
    int wv   = threadIdx.x >> 6;      // 0..3
    int lane = threadIdx.x & 63;
    int b    = blockIdx.x / HH;       // image 0..3
    int h    = blockIdx.x % HH;       // row
    int c    = wv >> 1;               // channel
    int half = wv & 1;                // x-half 0: [0,160)  1: [160,320)
    int row  = (2 * b + c) * HH + h;  // g2 row index

    __shared__ __align__(16) float sa[4][160];   // a[x]=x^2+g2[x], per wave (its half)
    __shared__ float pd[2][5][64];               // hi-half partial mins
    __shared__ float sd2[2][WW];                 // [channel][j] = actual d2

    const float* grow = g2 + (size_t)row * WW + half * 160;
    #pragma unroll
    for (int m = 0; m < 3; ++m) {
        int x = lane + 64 * m;
        if (x < 160) {
            float fx = (float)(x + half * 160);
            sa[wv][x] = fmaf(fx, fx, grow[x]);
        }
    }
    // sa is wave-private; same-wave LDS write->read ordering suffices

    const float4* sv = (const float4*)sa[wv];
    float d2v[5], n2j[5];
    #pragma unroll
    for (int m = 0; m < 5; ++m) {
        d2v[m] = 3.4e38f;
        n2j[m] = -2.0f * (float)(lane + 64 * m);
    }

    float xbase = (float)(half * 160);           // 0 or 160, exact
    #pragma unroll
    for (int t = 0; t < 5; ++t) {
        float4 cur[8];
        #pragma unroll
        for (int q = 0; q < 8; ++q) cur[q] = sv[8 * t + q];   // broadcast b128
        #pragma unroll
        for (int q = 0; q < 8; ++q) {
            float a0 = cur[q].x, a1 = cur[q].y, a2 = cur[q].z, a3 = cur[q].w;
            float x0 = xbase + (float)(32 * t + 4 * q);       // <= 348, exact
            #pragma unroll
            for (int m = 0; m < 5; ++m) {
                float t0 = fmaf(n2j[m], x0,        a0);
                float t1 = fmaf(n2j[m], x0 + 1.0f, a1);
                float t2 = fmaf(n2j[m], x0 + 2.0f, a2);
                float t3 = fmaf(n2j[m], x0 + 3.0f, a3);
                d2v[m] = fminf(fminf(d2v[m], fminf(t0, t1)), fminf(t2, t3));
            }
        }
    }

    if (half) {
        #pragma unroll
        for (int m = 0; m < 5; ++m) pd[c][m][lane] = d2v[m];
    }
    __syncthreads();
    if (!half) {
        #pragma unroll
        for (int m = 0; m < 5; ++m) {
            float dmin = fminf(d2v[m], pd[c][m][lane]);
            float fj = (float)(lane + 64 * m);
            sd2[c][lane + 64 * m] = fmaf(fj, fj, dmin);       // actual d2
        }
    }
    __syncthreads();

    // cooperative coalesced write: 320 j x 6 ch = 480 float4 for this row
    float* obase = out + (size_t)(b * HH + h) * WW * 6;
    for (int q = threadIdx.x; q < 480; q += 256) {
        int D = 4 * q;
        float vals[4];
        #pragma unroll
        for (int e = 0; e < 4; ++e) {
            int idx = D + e;
            int jj = idx / 6;
            int cs = idx - 6 * jj;                 // output channel 0..5
            int c2 = (cs >= 3) ? 1 : 0;
            int s  = cs - 3 * c2;
            float dd = sd2[c2][jj];
            float co = (s == 0) ? (1.0f / 81.92f)
                     : (s == 1) ? (1.0f / 1310.72f)
                                : (1.0f / 5242.88f);
            vals[e] = __expf(-dd * co);
        }
        float4 o = {vals[0], vals[1], vals[2], vals[3]};
        *(float4*)(obase + D) = o;
    }
}

extern "C" void kernel_launch(void* const* d_in, const int* in_sizes, int n_in,
                              void* d_out, int out_size, void* d_ws, size_t ws_size,
                              hipStream_t stream) {
    const float* in = (const float*)d_in[0];
    float* out = (float*)d_out;
    float* g2 = (float*)d_ws;   // 8*H*W floats = 3.27 MB scratch

    edt_vert<<<8 * 20, dim3(TW, NCH), 0, stream>>>(in, g2);
    edt_horiz<<<4 * HH, 256, 0, stream>>>(g2, out);
}